// Round 21
// baseline (148.113 us; speedup 1.0000x reference)
//
#include <hip/hip_runtime.h>
#include <hip/hip_bf16.h>
#include <cstdint>

#define BB 16
#define DD 64
#define LL 2048
#define NQ (BB*LL)          // 32768 queries
#define KK 8192             // codebook entries
#define VQ_SIZE (BB*DD*LL)  // 2097152 floats
#define CHUNK 256
#define NCH (KK/CHUNK)      // 32 chunks
#define QSL 64              // query slices per chunk (r21: halve active waves again)
#define QPS (NQ/QSL)        // 512 queries per slice (8 bitmap words)
#define MARGIN 0.75f        // > worst-case 2*eps_bf16 (~0.60) + slack

typedef __attribute__((ext_vector_type(8))) short short8;
typedef __attribute__((ext_vector_type(4))) float f32x4;
typedef unsigned long long u64;

// d_out region reuse (r20 layout):
//   [0, 4MB)  xb bf16 row-major [NQ][64]  } both dead after vq_cand ->
//   [4, 8MB)  cmaxT f32 [NCH][NQ]         }   xf f32 [NQ][64] (8 MB exactly)
//   [8MB, +128KB) indices region: qmask[NCH][NQ/64] u64 (exactly 128 KB),
//                 overwritten with float indices by vq_gather at the end.
// d_ws: nh2[KK] f32 [0,32K) + keys[NQ] u64 [32K,288K)  (proven)
//       cb16s bf16 pre-swizzled [544K, 544K+1M)  (gated: ws>=1605632; r16
//       proved ws>=544K — the extra 1M is gated with an identical fallback)

static __device__ inline short f2bf(float f) {   // RNE f32 -> bf16 (HW cvt)
    __hip_bfloat16 h = __float2bfloat16(f);
    return __builtin_bit_cast(short, h);
}

// DPP wave64 min-reduce step (pure VALU; proven r10-r20)
#define FMIN_DPP(v, ctrl)                                                     \
    do {                                                                      \
        int _vi = __float_as_int(v);                                          \
        int _sh = __builtin_amdgcn_update_dpp(_vi, _vi, (ctrl), 0xf, 0xf, false); \
        (v) = fminf((v), __int_as_float(_sh));                                \
    } while (0)

// DPP row-of-16 max-reduce step (lane 15 of each 16-lane row holds row max)
#define FMAX_DPP(v, ctrl)                                                     \
    do {                                                                      \
        int _vi = __float_as_int(v);                                          \
        int _sh = __builtin_amdgcn_update_dpp(_vi, _vi, (ctrl), 0xf, 0xf, false); \
        (v) = fmaxf((v), __int_as_float(_sh));                                \
    } while (0)

// ---- prep: z_e -> X_bf16 row-major [B*L][D]; blocks y==0 also fill nh2 ----
__global__ __launch_bounds__(256) void prep_x(const float* __restrict__ ze,
                                              short* __restrict__ xb,
                                              const float* __restrict__ cbf,
                                              float* __restrict__ nh2) {
    if (blockIdx.y == 0) {   // fused norm computation: 16 blocks x 256 thr x 2 k
        int k0 = blockIdx.x * 256 + threadIdx.x;
        #pragma unroll
        for (int r = 0; r < 2; ++r) {
            int k = k0 + r * 4096;
            const float4* c4 = (const float4*)(cbf + (size_t)k * DD);
            float s = 0.f;
            #pragma unroll
            for (int i = 0; i < DD / 4; ++i) {
                float4 v = c4[i];
                s += v.x * v.x + v.y * v.y + v.z * v.z + v.w * v.w;
            }
            nh2[k] = -0.5f * s;
        }
    }
    __shared__ float t[64][65];
    const int b = blockIdx.x;
    const int l0 = blockIdx.y * 64;
    const int tid = threadIdx.x;
    #pragma unroll
    for (int it = 0; it < 4; ++it) {
        int id = it * 256 + tid;
        int d = id >> 4;
        int lw = (id & 15) * 4;
        const float4 v = *(const float4*)(ze + ((size_t)b * DD + d) * LL + l0 + lw);
        t[d][lw + 0] = v.x; t[d][lw + 1] = v.y; t[d][lw + 2] = v.z; t[d][lw + 3] = v.w;
    }
    __syncthreads();
    #pragma unroll
    for (int it = 0; it < 2; ++it) {
        int id = it * 256 + tid;
        int lr = id >> 3;
        int u = id & 7;
        short8 o;
        #pragma unroll
        for (int e = 0; e < 8; ++e) o[e] = f2bf(t[u * 8 + e][lr]);
        *(short8*)(xb + (size_t)(b * LL + l0 + lr) * DD + u * 8) = o;
    }
}

// ---- prep: codebook f32 -> bf16, PRE-SWIZZLED unit order (r19-proven) ----
__global__ __launch_bounds__(256) void prep_cb16(const float* __restrict__ cbf,
                                                 short* __restrict__ cb16s) {
    int gi = blockIdx.x * 256 + threadIdx.x;   // unit id 0..KK*8-1
    int row = gi >> 3;
    int w = gi & 7;
    int col = (w ^ (row & 7)) * 8;
    const float4 lo = *(const float4*)(cbf + (size_t)row * DD + col);
    const float4 hi = *(const float4*)(cbf + (size_t)row * DD + col + 4);
    short8 o;
    o[0] = f2bf(lo.x); o[1] = f2bf(lo.y); o[2] = f2bf(lo.z); o[3] = f2bf(lo.w);
    o[4] = f2bf(hi.x); o[5] = f2bf(hi.y); o[6] = f2bf(hi.z); o[7] = f2bf(hi.w);
    *(short8*)(cb16s + (size_t)gi * 8) = o;
}

// ---- prep: z_e -> xf f32 [B*L][D] (contiguous rows for exact pass) ----
__global__ __launch_bounds__(256) void prep_xf(const float* __restrict__ ze,
                                               float* __restrict__ xf) {
    __shared__ float t[64][65];
    const int b = blockIdx.x;
    const int l0 = blockIdx.y * 64;
    const int tid = threadIdx.x;
    #pragma unroll
    for (int it = 0; it < 4; ++it) {
        int id = it * 256 + tid;
        int d = id >> 4;
        int lw = (id & 15) * 4;
        const float4 v = *(const float4*)(ze + ((size_t)b * DD + d) * LL + l0 + lw);
        t[d][lw + 0] = v.x; t[d][lw + 1] = v.y; t[d][lw + 2] = v.z; t[d][lw + 3] = v.w;
    }
    __syncthreads();
    #pragma unroll
    for (int it = 0; it < 4; ++it) {
        int id = it * 256 + tid;
        int row = id >> 4;
        int u = id & 15;
        float4 o = make_float4(t[4 * u + 0][row], t[4 * u + 1][row],
                               t[4 * u + 2][row], t[4 * u + 3][row]);
        *(float4*)(xf + (size_t)(b * LL + l0 + row) * DD + u * 4) = o;
    }
}

// ---- Phase A: bf16 MFMA screen, 512 queries/block (r20 structure);
//      CB16 variant stages pre-swizzled bf16 codebook as a linear copy ----
template <bool CB16>
__global__ __launch_bounds__(256) void vq_screen(const float* __restrict__ cbf,
                                                 const short* __restrict__ cb16s,
                                                 const float* __restrict__ nh2,
                                                 const short* __restrict__ xb,
                                                 float* __restrict__ cmaxT) {
    __shared__ short cbt[CHUNK * 64];   // 32KB, XOR-swizzled bf16 chunk
    __shared__ float sh2[CHUNK];
    const int tid = threadIdx.x;
    const int lane = tid & 63;
    const int wid = tid >> 6;
    const int kbase = blockIdx.y * CHUNK;
    const int qbase = blockIdx.x * 512 + wid * 128;   // 128 queries per wave
    const int r16 = lane & 15, g = lane >> 4;

    if (CB16) {   // pre-swizzled bf16 codebook: pure linear copy, no cvt
        #pragma unroll
        for (int it = 0; it < 8; ++it) {
            int id = it * 256 + tid;
            *(short8*)(&cbt[id * 8]) =
                *(const short8*)(cb16s + (size_t)kbase * 64 + (size_t)id * 8);
        }
    } else {      // fallback: convert f32 codebook per block (r20-identical)
        #pragma unroll
        for (int it = 0; it < 8; ++it) {
            int id = it * 256 + tid;
            int row = id >> 3;
            int u = id & 7;
            const float4 lo = *(const float4*)(cbf + (size_t)(kbase + row) * 64 + u * 8);
            const float4 hi = *(const float4*)(cbf + (size_t)(kbase + row) * 64 + u * 8 + 4);
            short8 o;
            o[0] = f2bf(lo.x); o[1] = f2bf(lo.y); o[2] = f2bf(lo.z); o[3] = f2bf(lo.w);
            o[4] = f2bf(hi.x); o[5] = f2bf(hi.y); o[6] = f2bf(hi.z); o[7] = f2bf(hi.w);
            *(short8*)(&cbt[row * 64 + ((u ^ (row & 7)) * 8)]) = o;
        }
    }
    sh2[tid] = nh2[kbase + tid];
    __syncthreads();

    short8 a[8][2];                       // 8 M-tiles x 2 k-steps
    #pragma unroll
    for (int t = 0; t < 8; ++t)
        #pragma unroll
        for (int ks = 0; ks < 2; ++ks)
            a[t][ks] = *(const short8*)(xb + (size_t)(qbase + t * 16 + r16) * 64 + ks * 32 + g * 8);

    float rm[8][4];
    #pragma unroll
    for (int t = 0; t < 8; ++t)
        #pragma unroll
        for (int j = 0; j < 4; ++j) rm[t][j] = -3.4e38f;

    for (int cs = 0; cs < CHUNK / 16; ++cs) {
        const int rowb = cs * 16 + r16;
        const float nh = sh2[rowb];
        const f32x4 ci = {nh, nh, nh, nh};
        const short8 b0 = *(const short8*)(&cbt[rowb * 64 + ((g ^ (rowb & 7)) * 8)]);
        const short8 b1 = *(const short8*)(&cbt[rowb * 64 + (((g + 4) ^ (rowb & 7)) * 8)]);
        #pragma unroll
        for (int t = 0; t < 8; ++t) {
            f32x4 acc = __builtin_amdgcn_mfma_f32_16x16x32_bf16(a[t][0], b0, ci, 0, 0, 0);
            acc = __builtin_amdgcn_mfma_f32_16x16x32_bf16(a[t][1], b1, acc, 0, 0, 0);
            rm[t][0] = fmaxf(rm[t][0], acc[0]);
            rm[t][1] = fmaxf(rm[t][1], acc[1]);
            rm[t][2] = fmaxf(rm[t][2], acc[2]);
            rm[t][3] = fmaxf(rm[t][3], acc[3]);
        }
    }

    // DPP row-of-16 max (VALU only); lane r16==15 holds each row's max
    #pragma unroll
    for (int t = 0; t < 8; ++t)
        #pragma unroll
        for (int j = 0; j < 4; ++j) {
            FMAX_DPP(rm[t][j], 0x111);   // row_shr:1
            FMAX_DPP(rm[t][j], 0x112);   // row_shr:2
            FMAX_DPP(rm[t][j], 0x114);   // row_shr:4
            FMAX_DPP(rm[t][j], 0x118);   // row_shr:8
        }

    if (r16 == 15) {   // transposed write: cmaxT[ch][q]; row = g*4 + j
        #pragma unroll
        for (int t = 0; t < 8; ++t)
            #pragma unroll
            for (int j = 0; j < 4; ++j)
                cmaxT[(size_t)blockIdx.y * NQ + (qbase + t * 16 + g * 4 + j)] = rm[t][j];
    }
}

// ---- Phase B1: candidate bitmap via ballot (atomic-free, deterministic) ----
__global__ __launch_bounds__(256) void vq_cand(const float* __restrict__ cmaxT,
                                               u64* __restrict__ qmask,
                                               u64* __restrict__ keys) {
    const int tid = threadIdx.x;
    const int lane = tid & 63;
    const int q = blockIdx.x * 256 + tid;
    const int qword = q >> 6;   // wave-uniform
    float v[NCH];
    float m = -3.4e38f;
    #pragma unroll
    for (int j = 0; j < NCH; ++j) {
        v[j] = cmaxT[(size_t)j * NQ + q];
        m = fmaxf(m, v[j]);
    }
    keys[q] = ~0ULL;
    const float thr = m - MARGIN;
    #pragma unroll
    for (int j = 0; j < NCH; ++j) {
        u64 mm = __ballot(v[j] >= thr);
        if (lane == 0) qmask[(size_t)j * (NQ / 64) + qword] = mm;
    }
}

// ---- Phase B2: exact fp32 pass (r20 structure; QPS=512 -> 8 bitmap words,
//      halving active-wave count again so cdv prologue amortizes further) ----
__global__ __launch_bounds__(256, 2) void vq_exact(const float* __restrict__ xf,
                                                   const float* __restrict__ cbf,
                                                   const float* __restrict__ nh2,
                                                   const u64* __restrict__ qmask,
                                                   u64* __restrict__ keys) {
    const int ch = blockIdx.x;
    const int slice = blockIdx.y;                 // 0..QSL-1
    const int lane = threadIdx.x & 63;
    const int wid = threadIdx.x >> 6;
    const int kb = ch * CHUNK + wid * 64;
    const int k = kb + lane;

    const u64* wm = qmask + (size_t)ch * (NQ / 64) + slice * (QPS / 64);
    u64 words[QPS / 64];
    u64 any = 0;
    #pragma unroll
    for (int w = 0; w < QPS / 64; ++w) {
        u64 x = wm[w];
        uint32_t lo = __builtin_amdgcn_readfirstlane((uint32_t)x);
        uint32_t hi = __builtin_amdgcn_readfirstlane((uint32_t)(x >> 32));
        words[w] = ((u64)hi << 32) | lo;          // SALU-resident
        any |= words[w];
    }
    if (!any) return;                             // skip code load entirely

    f32x4 cdv[16];                                // this lane's code row
    const f32x4* cb4 = (const f32x4*)(cbf + (size_t)k * DD);
    #pragma unroll
    for (int i = 0; i < 16; ++i) cdv[i] = cb4[i];
    const float nh2k = nh2[k];

    #pragma unroll 1
    for (int w = 0; w < QPS / 64; ++w) {
        u64 sw = words[w];
        while (sw) {
            const int bit = __ffsll((long long)sw) - 1;
            sw &= sw - 1;
            const int q = slice * QPS + w * 64 + bit;
            const f32x4* xr4 = (const f32x4*)(xf + (size_t)q * DD);
            f32x4 xv[16];                          // 16 independent loads in flight
            #pragma unroll
            for (int i = 0; i < 16; ++i) xv[i] = xr4[i];

            float a0 = 0.f, a1 = 0.f, a2 = 0.f, a3 = 0.f;
            #pragma unroll
            for (int i = 0; i < 16; ++i) {         // 4 independent fma chains
                a0 = fmaf(xv[i].x, cdv[i].x, a0);
                a1 = fmaf(xv[i].y, cdv[i].y, a1);
                a2 = fmaf(xv[i].z, cdv[i].z, a2);
                a3 = fmaf(xv[i].w, cdv[i].w, a3);
            }
            float val = -(((a0 + a1) + (a2 + a3)) + nh2k);

            float mn = val;                        // DPP wave64 min (VALU only)
            FMIN_DPP(mn, 0x111);
            FMIN_DPP(mn, 0x112);
            FMIN_DPP(mn, 0x114);
            FMIN_DPP(mn, 0x118);
            FMIN_DPP(mn, 0x142);
            FMIN_DPP(mn, 0x143);
            const float mnall = __uint_as_float(
                __builtin_amdgcn_readlane(__float_as_uint(mn), 63));

            u64 mk = __ballot(val == mnall);       // lane order = code order
            int srcl = __ffsll((long long)mk) - 1; // lowest index on ties
            uint32_t uu = __float_as_uint(mnall);
            uint32_t ub = ((int)uu < 0) ? ~uu : (uu | 0x80000000u);
            u64 key = ((u64)ub << 32) | (unsigned)(kb + srcl);
            if (lane == 0) atomicMin(&keys[q], key);
        }
    }
}

// ---- final: v_q gather + index write (d==0 threads emit indices) ----
__global__ __launch_bounds__(256) void vq_gather(const float* __restrict__ cb,
                                                 const u64* __restrict__ keys,
                                                 float* __restrict__ vq,
                                                 float* __restrict__ oidx) {
    int t = blockIdx.x * 256 + threadIdx.x;
    int l = t & (LL - 1);
    int bd = t >> 11;
    int d = bd & 63;
    int b = bd >> 6;
    int idx = (int)(unsigned)(keys[b * LL + l] & 0x1FFFu);
    vq[t] = cb[idx * DD + d];
    if (d == 0) oidx[b * LL + l] = (float)idx;
}

extern "C" void kernel_launch(void* const* d_in, const int* in_sizes, int n_in,
                              void* d_out, int out_size, void* d_ws, size_t ws_size,
                              hipStream_t stream) {
    const float* ze = (const float*)d_in[0];
    const float* cb = (const float*)d_in[1];
    float* out = (float*)d_out;

    short* xb = (short*)d_out;                                    // [0,4MB)
    float* cmaxT = (float*)((char*)d_out + (size_t)NQ * DD * 2);  // [4,8MB)
    float* xf = (float*)d_out;                                    // [0,8MB) after cand
    u64* qmask = (u64*)(out + VQ_SIZE);                           // 128KB indices region
    float* nh2 = (float*)d_ws;                                    // [0,32K)
    u64* keys = (u64*)((char*)d_ws + (size_t)KK * 4);             // [32K,288K)
    short* cb16s = (short*)((char*)d_ws + (size_t)544 * 1024);    // [544K,544K+1M)
    float* oidx = out + VQ_SIZE;

    const bool cb16 = ws_size >= (size_t)(544 * 1024 + (size_t)KK * DD * 2);

    dim3 gx(BB, LL / 64);
    prep_x<<<gx, 256, 0, stream>>>(ze, xb, cb, nh2);   // nh2 fused (y==0 blocks)
    if (cb16) prep_cb16<<<(KK * 8) / 256, 256, 0, stream>>>(cb, cb16s);

    dim3 gs(NQ / 512, NCH);
    if (cb16) vq_screen<true><<<gs, 256, 0, stream>>>(cb, cb16s, nh2, xb, cmaxT);
    else      vq_screen<false><<<gs, 256, 0, stream>>>(cb, cb16s, nh2, xb, cmaxT);

    vq_cand<<<NQ / 256, 256, 0, stream>>>(cmaxT, qmask, keys);

    prep_xf<<<gx, 256, 0, stream>>>(ze, xf);   // overwrites xb+cmaxT (both dead)

    dim3 ge(NCH, QSL);
    vq_exact<<<ge, 256, 0, stream>>>(xf, cb, nh2, qmask, keys);

    vq_gather<<<VQ_SIZE / 256, 256, 0, stream>>>(cb, keys, out, oidx);
}

// Round 22
// 142.794 us; speedup vs baseline: 1.0373x; 1.0373x over previous
//
#include <hip/hip_runtime.h>
#include <hip/hip_bf16.h>
#include <cstdint>

#define BB 16
#define DD 64
#define LL 2048
#define NQ (BB*LL)          // 32768 queries
#define KK 8192             // codebook entries
#define VQ_SIZE (BB*DD*LL)  // 2097152 floats
#define CHUNK 256
#define NCH (KK/CHUNK)      // 32 chunks
#define QSL 128             // query slices per chunk (r20-proven optimum)
#define QPS (NQ/QSL)        // 256 queries per slice (4 bitmap words)
#define MARGIN 0.75f        // > worst-case 2*eps_bf16 (~0.60) + slack

typedef __attribute__((ext_vector_type(8))) short short8;
typedef __attribute__((ext_vector_type(4))) float f32x4;
typedef unsigned long long u64;

// d_out region reuse (r20 layout):
//   [0, 4MB)  xb bf16 row-major [NQ][64]  } both dead after vq_cand ->
//   [4, 8MB)  cmaxT f32 [NCH][NQ]         }   xf f32 [NQ][64] (8 MB exactly)
//   [8MB, +128KB) indices region: qmask[NCH][NQ/64] u64 (exactly 128 KB),
//                 overwritten with float indices by vq_gather at the end.
// d_ws: nh2[KK] f32 [0,32K) + keys[NQ] u64 [32K,288K)  (proven)
//       cb16s bf16 pre-swizzled [544K, 544K+1M)  (gated: ws>=1605632;
//       engaged in r21 per the rest-delta — fallback identical to r20)

static __device__ inline short f2bf(float f) {   // RNE f32 -> bf16 (HW cvt)
    __hip_bfloat16 h = __float2bfloat16(f);
    return __builtin_bit_cast(short, h);
}

// DPP wave64 min-reduce step (pure VALU; proven r10-r21)
#define FMIN_DPP(v, ctrl)                                                     \
    do {                                                                      \
        int _vi = __float_as_int(v);                                          \
        int _sh = __builtin_amdgcn_update_dpp(_vi, _vi, (ctrl), 0xf, 0xf, false); \
        (v) = fminf((v), __int_as_float(_sh));                                \
    } while (0)

// DPP row-of-16 max-reduce step (lane 15 of each 16-lane row holds row max)
#define FMAX_DPP(v, ctrl)                                                     \
    do {                                                                      \
        int _vi = __float_as_int(v);                                          \
        int _sh = __builtin_amdgcn_update_dpp(_vi, _vi, (ctrl), 0xf, 0xf, false); \
        (v) = fmaxf((v), __int_as_float(_sh));                                \
    } while (0)

// ---- prep: z_e -> X_bf16 row-major [B*L][D]; blocks y==0 also fill nh2 ----
__global__ __launch_bounds__(256) void prep_x(const float* __restrict__ ze,
                                              short* __restrict__ xb,
                                              const float* __restrict__ cbf,
                                              float* __restrict__ nh2) {
    if (blockIdx.y == 0) {   // fused norm computation: 16 blocks x 256 thr x 2 k
        int k0 = blockIdx.x * 256 + threadIdx.x;
        #pragma unroll
        for (int r = 0; r < 2; ++r) {
            int k = k0 + r * 4096;
            const float4* c4 = (const float4*)(cbf + (size_t)k * DD);
            float s = 0.f;
            #pragma unroll
            for (int i = 0; i < DD / 4; ++i) {
                float4 v = c4[i];
                s += v.x * v.x + v.y * v.y + v.z * v.z + v.w * v.w;
            }
            nh2[k] = -0.5f * s;
        }
    }
    __shared__ float t[64][65];
    const int b = blockIdx.x;
    const int l0 = blockIdx.y * 64;
    const int tid = threadIdx.x;
    #pragma unroll
    for (int it = 0; it < 4; ++it) {
        int id = it * 256 + tid;
        int d = id >> 4;
        int lw = (id & 15) * 4;
        const float4 v = *(const float4*)(ze + ((size_t)b * DD + d) * LL + l0 + lw);
        t[d][lw + 0] = v.x; t[d][lw + 1] = v.y; t[d][lw + 2] = v.z; t[d][lw + 3] = v.w;
    }
    __syncthreads();
    #pragma unroll
    for (int it = 0; it < 2; ++it) {
        int id = it * 256 + tid;
        int lr = id >> 3;
        int u = id & 7;
        short8 o;
        #pragma unroll
        for (int e = 0; e < 8; ++e) o[e] = f2bf(t[u * 8 + e][lr]);
        *(short8*)(xb + (size_t)(b * LL + l0 + lr) * DD + u * 8) = o;
    }
}

// ---- prep: codebook f32 -> bf16, PRE-SWIZZLED unit order (r21-proven) ----
__global__ __launch_bounds__(256) void prep_cb16(const float* __restrict__ cbf,
                                                 short* __restrict__ cb16s) {
    int gi = blockIdx.x * 256 + threadIdx.x;   // unit id 0..KK*8-1
    int row = gi >> 3;
    int w = gi & 7;
    int col = (w ^ (row & 7)) * 8;
    const float4 lo = *(const float4*)(cbf + (size_t)row * DD + col);
    const float4 hi = *(const float4*)(cbf + (size_t)row * DD + col + 4);
    short8 o;
    o[0] = f2bf(lo.x); o[1] = f2bf(lo.y); o[2] = f2bf(lo.z); o[3] = f2bf(lo.w);
    o[4] = f2bf(hi.x); o[5] = f2bf(hi.y); o[6] = f2bf(hi.z); o[7] = f2bf(hi.w);
    *(short8*)(cb16s + (size_t)gi * 8) = o;
}

// ---- prep: z_e -> xf f32 [B*L][D] (contiguous rows for exact pass) ----
__global__ __launch_bounds__(256) void prep_xf(const float* __restrict__ ze,
                                               float* __restrict__ xf) {
    __shared__ float t[64][65];
    const int b = blockIdx.x;
    const int l0 = blockIdx.y * 64;
    const int tid = threadIdx.x;
    #pragma unroll
    for (int it = 0; it < 4; ++it) {
        int id = it * 256 + tid;
        int d = id >> 4;
        int lw = (id & 15) * 4;
        const float4 v = *(const float4*)(ze + ((size_t)b * DD + d) * LL + l0 + lw);
        t[d][lw + 0] = v.x; t[d][lw + 1] = v.y; t[d][lw + 2] = v.z; t[d][lw + 3] = v.w;
    }
    __syncthreads();
    #pragma unroll
    for (int it = 0; it < 4; ++it) {
        int id = it * 256 + tid;
        int row = id >> 4;
        int u = id & 15;
        float4 o = make_float4(t[4 * u + 0][row], t[4 * u + 1][row],
                               t[4 * u + 2][row], t[4 * u + 3][row]);
        *(float4*)(xf + (size_t)(b * LL + l0 + row) * DD + u * 4) = o;
    }
}

// ---- Phase A: bf16 MFMA screen, 512 queries/block (r20 structure);
//      CB16 variant stages pre-swizzled bf16 codebook as a linear copy ----
template <bool CB16>
__global__ __launch_bounds__(256) void vq_screen(const float* __restrict__ cbf,
                                                 const short* __restrict__ cb16s,
                                                 const float* __restrict__ nh2,
                                                 const short* __restrict__ xb,
                                                 float* __restrict__ cmaxT) {
    __shared__ short cbt[CHUNK * 64];   // 32KB, XOR-swizzled bf16 chunk
    __shared__ float sh2[CHUNK];
    const int tid = threadIdx.x;
    const int lane = tid & 63;
    const int wid = tid >> 6;
    const int kbase = blockIdx.y * CHUNK;
    const int qbase = blockIdx.x * 512 + wid * 128;   // 128 queries per wave
    const int r16 = lane & 15, g = lane >> 4;

    if (CB16) {   // pre-swizzled bf16 codebook: pure linear copy, no cvt
        #pragma unroll
        for (int it = 0; it < 8; ++it) {
            int id = it * 256 + tid;
            *(short8*)(&cbt[id * 8]) =
                *(const short8*)(cb16s + (size_t)kbase * 64 + (size_t)id * 8);
        }
    } else {      // fallback: convert f32 codebook per block (r20-identical)
        #pragma unroll
        for (int it = 0; it < 8; ++it) {
            int id = it * 256 + tid;
            int row = id >> 3;
            int u = id & 7;
            const float4 lo = *(const float4*)(cbf + (size_t)(kbase + row) * 64 + u * 8);
            const float4 hi = *(const float4*)(cbf + (size_t)(kbase + row) * 64 + u * 8 + 4);
            short8 o;
            o[0] = f2bf(lo.x); o[1] = f2bf(lo.y); o[2] = f2bf(lo.z); o[3] = f2bf(lo.w);
            o[4] = f2bf(hi.x); o[5] = f2bf(hi.y); o[6] = f2bf(hi.z); o[7] = f2bf(hi.w);
            *(short8*)(&cbt[row * 64 + ((u ^ (row & 7)) * 8)]) = o;
        }
    }
    sh2[tid] = nh2[kbase + tid];
    __syncthreads();

    short8 a[8][2];                       // 8 M-tiles x 2 k-steps
    #pragma unroll
    for (int t = 0; t < 8; ++t)
        #pragma unroll
        for (int ks = 0; ks < 2; ++ks)
            a[t][ks] = *(const short8*)(xb + (size_t)(qbase + t * 16 + r16) * 64 + ks * 32 + g * 8);

    float rm[8][4];
    #pragma unroll
    for (int t = 0; t < 8; ++t)
        #pragma unroll
        for (int j = 0; j < 4; ++j) rm[t][j] = -3.4e38f;

    for (int cs = 0; cs < CHUNK / 16; ++cs) {
        const int rowb = cs * 16 + r16;
        const float nh = sh2[rowb];
        const f32x4 ci = {nh, nh, nh, nh};
        const short8 b0 = *(const short8*)(&cbt[rowb * 64 + ((g ^ (rowb & 7)) * 8)]);
        const short8 b1 = *(const short8*)(&cbt[rowb * 64 + (((g + 4) ^ (rowb & 7)) * 8)]);
        #pragma unroll
        for (int t = 0; t < 8; ++t) {
            f32x4 acc = __builtin_amdgcn_mfma_f32_16x16x32_bf16(a[t][0], b0, ci, 0, 0, 0);
            acc = __builtin_amdgcn_mfma_f32_16x16x32_bf16(a[t][1], b1, acc, 0, 0, 0);
            rm[t][0] = fmaxf(rm[t][0], acc[0]);
            rm[t][1] = fmaxf(rm[t][1], acc[1]);
            rm[t][2] = fmaxf(rm[t][2], acc[2]);
            rm[t][3] = fmaxf(rm[t][3], acc[3]);
        }
    }

    // DPP row-of-16 max (VALU only); lane r16==15 holds each row's max
    #pragma unroll
    for (int t = 0; t < 8; ++t)
        #pragma unroll
        for (int j = 0; j < 4; ++j) {
            FMAX_DPP(rm[t][j], 0x111);   // row_shr:1
            FMAX_DPP(rm[t][j], 0x112);   // row_shr:2
            FMAX_DPP(rm[t][j], 0x114);   // row_shr:4
            FMAX_DPP(rm[t][j], 0x118);   // row_shr:8
        }

    if (r16 == 15) {   // transposed write: cmaxT[ch][q]; row = g*4 + j
        #pragma unroll
        for (int t = 0; t < 8; ++t)
            #pragma unroll
            for (int j = 0; j < 4; ++j)
                cmaxT[(size_t)blockIdx.y * NQ + (qbase + t * 16 + g * 4 + j)] = rm[t][j];
    }
}

// ---- Phase B1: candidate bitmap via ballot (atomic-free, deterministic) ----
__global__ __launch_bounds__(256) void vq_cand(const float* __restrict__ cmaxT,
                                               u64* __restrict__ qmask,
                                               u64* __restrict__ keys) {
    const int tid = threadIdx.x;
    const int lane = tid & 63;
    const int q = blockIdx.x * 256 + tid;
    const int qword = q >> 6;   // wave-uniform
    float v[NCH];
    float m = -3.4e38f;
    #pragma unroll
    for (int j = 0; j < NCH; ++j) {
        v[j] = cmaxT[(size_t)j * NQ + q];
        m = fmaxf(m, v[j]);
    }
    keys[q] = ~0ULL;
    const float thr = m - MARGIN;
    #pragma unroll
    for (int j = 0; j < NCH; ++j) {
        u64 mm = __ballot(v[j] >= thr);
        if (lane == 0) qmask[(size_t)j * (NQ / 64) + qword] = mm;
    }
}

// ---- Phase B2: exact fp32 pass (r20 structure, QPS=256, proven 73.4 us) ----
__global__ __launch_bounds__(256, 2) void vq_exact(const float* __restrict__ xf,
                                                   const float* __restrict__ cbf,
                                                   const float* __restrict__ nh2,
                                                   const u64* __restrict__ qmask,
                                                   u64* __restrict__ keys) {
    const int ch = blockIdx.x;
    const int slice = blockIdx.y;                 // 0..QSL-1
    const int lane = threadIdx.x & 63;
    const int wid = threadIdx.x >> 6;
    const int kb = ch * CHUNK + wid * 64;
    const int k = kb + lane;

    const u64* wm = qmask + (size_t)ch * (NQ / 64) + slice * (QPS / 64);
    u64 words[QPS / 64];
    u64 any = 0;
    #pragma unroll
    for (int w = 0; w < QPS / 64; ++w) {
        u64 x = wm[w];
        uint32_t lo = __builtin_amdgcn_readfirstlane((uint32_t)x);
        uint32_t hi = __builtin_amdgcn_readfirstlane((uint32_t)(x >> 32));
        words[w] = ((u64)hi << 32) | lo;          // SALU-resident
        any |= words[w];
    }
    if (!any) return;                             // skip code load entirely

    f32x4 cdv[16];                                // this lane's code row
    const f32x4* cb4 = (const f32x4*)(cbf + (size_t)k * DD);
    #pragma unroll
    for (int i = 0; i < 16; ++i) cdv[i] = cb4[i];
    const float nh2k = nh2[k];

    #pragma unroll 1
    for (int w = 0; w < QPS / 64; ++w) {
        u64 sw = words[w];
        while (sw) {
            const int bit = __ffsll((long long)sw) - 1;
            sw &= sw - 1;
            const int q = slice * QPS + w * 64 + bit;
            const f32x4* xr4 = (const f32x4*)(xf + (size_t)q * DD);
            f32x4 xv[16];                          // 16 independent loads in flight
            #pragma unroll
            for (int i = 0; i < 16; ++i) xv[i] = xr4[i];

            float a0 = 0.f, a1 = 0.f, a2 = 0.f, a3 = 0.f;
            #pragma unroll
            for (int i = 0; i < 16; ++i) {         // 4 independent fma chains
                a0 = fmaf(xv[i].x, cdv[i].x, a0);
                a1 = fmaf(xv[i].y, cdv[i].y, a1);
                a2 = fmaf(xv[i].z, cdv[i].z, a2);
                a3 = fmaf(xv[i].w, cdv[i].w, a3);
            }
            float val = -(((a0 + a1) + (a2 + a3)) + nh2k);

            float mn = val;                        // DPP wave64 min (VALU only)
            FMIN_DPP(mn, 0x111);
            FMIN_DPP(mn, 0x112);
            FMIN_DPP(mn, 0x114);
            FMIN_DPP(mn, 0x118);
            FMIN_DPP(mn, 0x142);
            FMIN_DPP(mn, 0x143);
            const float mnall = __uint_as_float(
                __builtin_amdgcn_readlane(__float_as_uint(mn), 63));

            u64 mk = __ballot(val == mnall);       // lane order = code order
            int srcl = __ffsll((long long)mk) - 1; // lowest index on ties
            uint32_t uu = __float_as_uint(mnall);
            uint32_t ub = ((int)uu < 0) ? ~uu : (uu | 0x80000000u);
            u64 key = ((u64)ub << 32) | (unsigned)(kb + srcl);
            if (lane == 0) atomicMin(&keys[q], key);
        }
    }
}

// ---- final: v_q gather + index write (d==0 threads emit indices) ----
__global__ __launch_bounds__(256) void vq_gather(const float* __restrict__ cb,
                                                 const u64* __restrict__ keys,
                                                 float* __restrict__ vq,
                                                 float* __restrict__ oidx) {
    int t = blockIdx.x * 256 + threadIdx.x;
    int l = t & (LL - 1);
    int bd = t >> 11;
    int d = bd & 63;
    int b = bd >> 6;
    int idx = (int)(unsigned)(keys[b * LL + l] & 0x1FFFu);
    vq[t] = cb[idx * DD + d];
    if (d == 0) oidx[b * LL + l] = (float)idx;
}

extern "C" void kernel_launch(void* const* d_in, const int* in_sizes, int n_in,
                              void* d_out, int out_size, void* d_ws, size_t ws_size,
                              hipStream_t stream) {
    const float* ze = (const float*)d_in[0];
    const float* cb = (const float*)d_in[1];
    float* out = (float*)d_out;

    short* xb = (short*)d_out;                                    // [0,4MB)
    float* cmaxT = (float*)((char*)d_out + (size_t)NQ * DD * 2);  // [4,8MB)
    float* xf = (float*)d_out;                                    // [0,8MB) after cand
    u64* qmask = (u64*)(out + VQ_SIZE);                           // 128KB indices region
    float* nh2 = (float*)d_ws;                                    // [0,32K)
    u64* keys = (u64*)((char*)d_ws + (size_t)KK * 4);             // [32K,288K)
    short* cb16s = (short*)((char*)d_ws + (size_t)544 * 1024);    // [544K,544K+1M)
    float* oidx = out + VQ_SIZE;

    const bool cb16 = ws_size >= (size_t)(544 * 1024 + (size_t)KK * DD * 2);

    dim3 gx(BB, LL / 64);
    prep_x<<<gx, 256, 0, stream>>>(ze, xb, cb, nh2);   // nh2 fused (y==0 blocks)
    if (cb16) prep_cb16<<<(KK * 8) / 256, 256, 0, stream>>>(cb, cb16s);

    dim3 gs(NQ / 512, NCH);
    if (cb16) vq_screen<true><<<gs, 256, 0, stream>>>(cb, cb16s, nh2, xb, cmaxT);
    else      vq_screen<false><<<gs, 256, 0, stream>>>(cb, cb16s, nh2, xb, cmaxT);

    vq_cand<<<NQ / 256, 256, 0, stream>>>(cmaxT, qmask, keys);

    prep_xf<<<gx, 256, 0, stream>>>(ze, xf);   // overwrites xb+cmaxT (both dead)

    dim3 ge(NCH, QSL);
    vq_exact<<<ge, 256, 0, stream>>>(xf, cb, nh2, qmask, keys);

    vq_gather<<<VQ_SIZE / 256, 256, 0, stream>>>(cb, keys, out, oidx);
}

// Round 23
// 141.356 us; speedup vs baseline: 1.0478x; 1.0102x over previous
//
#include <hip/hip_runtime.h>
#include <hip/hip_bf16.h>
#include <cstdint>

#define BB 16
#define DD 64
#define LL 2048
#define NQ (BB*LL)          // 32768 queries
#define KK 8192             // codebook entries
#define VQ_SIZE (BB*DD*LL)  // 2097152 floats
#define CHUNK 256
#define NCH (KK/CHUNK)      // 32 chunks
#define QSL 128             // query slices per chunk (r20-proven optimum)
#define QPS (NQ/QSL)        // 256 queries per slice (4 bitmap words)
#define MARGIN 0.75f        // > worst-case 2*eps_bf16 (~0.60) + slack

typedef __attribute__((ext_vector_type(8))) short short8;
typedef __attribute__((ext_vector_type(4))) float f32x4;
typedef unsigned long long u64;

// d_out region reuse (r20 layout):
//   [0, 4MB)  xb bf16 row-major [NQ][64]  } both dead after vq_cand ->
//   [4, 8MB)  cmaxT f32 [NCH][NQ]         }   xf f32 [NQ][64] (8 MB exactly)
//   [8MB, +128KB) indices region: qmask[NCH][NQ/64] u64 (exactly 128 KB),
//                 overwritten with float indices by vq_gather at the end.
// d_ws: nh2[KK] f32 [0,32K) + keys[NQ] u64 [32K,288K)  (proven)
//       cb16s bf16 pre-swizzled [544K, 544K+1M)  (gated: ws>=1605632; engaged
//       since r21 — fallback path is byte-identical staging)

static __device__ inline short f2bf(float f) {   // RNE f32 -> bf16 (HW cvt)
    __hip_bfloat16 h = __float2bfloat16(f);
    return __builtin_bit_cast(short, h);
}

// DPP wave64 min-reduce step (pure VALU; proven r10-r22)
#define FMIN_DPP(v, ctrl)                                                     \
    do {                                                                      \
        int _vi = __float_as_int(v);                                          \
        int _sh = __builtin_amdgcn_update_dpp(_vi, _vi, (ctrl), 0xf, 0xf, false); \
        (v) = fminf((v), __int_as_float(_sh));                                \
    } while (0)

// DPP row-of-16 max-reduce step (lane 15 of each 16-lane row holds row max)
#define FMAX_DPP(v, ctrl)                                                     \
    do {                                                                      \
        int _vi = __float_as_int(v);                                          \
        int _sh = __builtin_amdgcn_update_dpp(_vi, _vi, (ctrl), 0xf, 0xf, false); \
        (v) = fmaxf((v), __int_as_float(_sh));                                \
    } while (0)

// ---- prep: z_e -> X_bf16 row-major [B*L][D]; blocks y==0 also fill nh2 ----
__global__ __launch_bounds__(256) void prep_x(const float* __restrict__ ze,
                                              short* __restrict__ xb,
                                              const float* __restrict__ cbf,
                                              float* __restrict__ nh2) {
    if (blockIdx.y == 0) {   // fused norm computation: 16 blocks x 256 thr x 2 k
        int k0 = blockIdx.x * 256 + threadIdx.x;
        #pragma unroll
        for (int r = 0; r < 2; ++r) {
            int k = k0 + r * 4096;
            const float4* c4 = (const float4*)(cbf + (size_t)k * DD);
            float s = 0.f;
            #pragma unroll
            for (int i = 0; i < DD / 4; ++i) {
                float4 v = c4[i];
                s += v.x * v.x + v.y * v.y + v.z * v.z + v.w * v.w;
            }
            nh2[k] = -0.5f * s;
        }
    }
    __shared__ float t[64][65];
    const int b = blockIdx.x;
    const int l0 = blockIdx.y * 64;
    const int tid = threadIdx.x;
    #pragma unroll
    for (int it = 0; it < 4; ++it) {
        int id = it * 256 + tid;
        int d = id >> 4;
        int lw = (id & 15) * 4;
        const float4 v = *(const float4*)(ze + ((size_t)b * DD + d) * LL + l0 + lw);
        t[d][lw + 0] = v.x; t[d][lw + 1] = v.y; t[d][lw + 2] = v.z; t[d][lw + 3] = v.w;
    }
    __syncthreads();
    #pragma unroll
    for (int it = 0; it < 2; ++it) {
        int id = it * 256 + tid;
        int lr = id >> 3;
        int u = id & 7;
        short8 o;
        #pragma unroll
        for (int e = 0; e < 8; ++e) o[e] = f2bf(t[u * 8 + e][lr]);
        *(short8*)(xb + (size_t)(b * LL + l0 + lr) * DD + u * 8) = o;
    }
}

// ---- prep: codebook f32 -> bf16, PRE-SWIZZLED unit order (r21-proven) ----
__global__ __launch_bounds__(256) void prep_cb16(const float* __restrict__ cbf,
                                                 short* __restrict__ cb16s) {
    int gi = blockIdx.x * 256 + threadIdx.x;   // unit id 0..KK*8-1
    int row = gi >> 3;
    int w = gi & 7;
    int col = (w ^ (row & 7)) * 8;
    const float4 lo = *(const float4*)(cbf + (size_t)row * DD + col);
    const float4 hi = *(const float4*)(cbf + (size_t)row * DD + col + 4);
    short8 o;
    o[0] = f2bf(lo.x); o[1] = f2bf(lo.y); o[2] = f2bf(lo.z); o[3] = f2bf(lo.w);
    o[4] = f2bf(hi.x); o[5] = f2bf(hi.y); o[6] = f2bf(hi.z); o[7] = f2bf(hi.w);
    *(short8*)(cb16s + (size_t)gi * 8) = o;
}

// ---- prep: z_e -> xf f32 [B*L][D] (contiguous rows for exact pass) ----
__global__ __launch_bounds__(256) void prep_xf(const float* __restrict__ ze,
                                               float* __restrict__ xf) {
    __shared__ float t[64][65];
    const int b = blockIdx.x;
    const int l0 = blockIdx.y * 64;
    const int tid = threadIdx.x;
    #pragma unroll
    for (int it = 0; it < 4; ++it) {
        int id = it * 256 + tid;
        int d = id >> 4;
        int lw = (id & 15) * 4;
        const float4 v = *(const float4*)(ze + ((size_t)b * DD + d) * LL + l0 + lw);
        t[d][lw + 0] = v.x; t[d][lw + 1] = v.y; t[d][lw + 2] = v.z; t[d][lw + 3] = v.w;
    }
    __syncthreads();
    #pragma unroll
    for (int it = 0; it < 4; ++it) {
        int id = it * 256 + tid;
        int row = id >> 4;
        int u = id & 15;
        float4 o = make_float4(t[4 * u + 0][row], t[4 * u + 1][row],
                               t[4 * u + 2][row], t[4 * u + 3][row]);
        *(float4*)(xf + (size_t)(b * LL + l0 + row) * DD + u * 4) = o;
    }
}

// ---- Phase A: bf16 MFMA screen, 512 queries/block, TWO chunks per block
//      (A-fragments loaded once, reused across both chunks) ----
template <bool CB16>
__global__ __launch_bounds__(256) void vq_screen(const float* __restrict__ cbf,
                                                 const short* __restrict__ cb16s,
                                                 const float* __restrict__ nh2,
                                                 const short* __restrict__ xb,
                                                 float* __restrict__ cmaxT) {
    __shared__ short cbt[CHUNK * 64];   // 32KB, XOR-swizzled bf16 chunk
    __shared__ float sh2[CHUNK];
    const int tid = threadIdx.x;
    const int lane = tid & 63;
    const int wid = tid >> 6;
    const int qbase = blockIdx.x * 512 + wid * 128;   // 128 queries per wave
    const int r16 = lane & 15, g = lane >> 4;

    // A-fragments loaded ONCE, reused for both chunks
    short8 a[8][2];
    #pragma unroll
    for (int t = 0; t < 8; ++t)
        #pragma unroll
        for (int ks = 0; ks < 2; ++ks)
            a[t][ks] = *(const short8*)(xb + (size_t)(qbase + t * 16 + r16) * 64 + ks * 32 + g * 8);

    #pragma unroll 1
    for (int cc = 0; cc < 2; ++cc) {
        const int chunk = blockIdx.y * 2 + cc;
        const int kbase = chunk * CHUNK;
        if (cc) __syncthreads();   // previous chunk's compute fully drained

        if (CB16) {   // pre-swizzled bf16 codebook: pure linear copy, no cvt
            #pragma unroll
            for (int it = 0; it < 8; ++it) {
                int id = it * 256 + tid;
                *(short8*)(&cbt[id * 8]) =
                    *(const short8*)(cb16s + (size_t)kbase * 64 + (size_t)id * 8);
            }
        } else {      // fallback: convert f32 codebook per block
            #pragma unroll
            for (int it = 0; it < 8; ++it) {
                int id = it * 256 + tid;
                int row = id >> 3;
                int u = id & 7;
                const float4 lo = *(const float4*)(cbf + (size_t)(kbase + row) * 64 + u * 8);
                const float4 hi = *(const float4*)(cbf + (size_t)(kbase + row) * 64 + u * 8 + 4);
                short8 o;
                o[0] = f2bf(lo.x); o[1] = f2bf(lo.y); o[2] = f2bf(lo.z); o[3] = f2bf(lo.w);
                o[4] = f2bf(hi.x); o[5] = f2bf(hi.y); o[6] = f2bf(hi.z); o[7] = f2bf(hi.w);
                *(short8*)(&cbt[row * 64 + ((u ^ (row & 7)) * 8)]) = o;
            }
        }
        sh2[tid] = nh2[kbase + tid];
        __syncthreads();

        float rm[8][4];
        #pragma unroll
        for (int t = 0; t < 8; ++t)
            #pragma unroll
            for (int j = 0; j < 4; ++j) rm[t][j] = -3.4e38f;

        for (int cs = 0; cs < CHUNK / 16; ++cs) {
            const int rowb = cs * 16 + r16;
            const float nh = sh2[rowb];
            const f32x4 ci = {nh, nh, nh, nh};
            const short8 b0 = *(const short8*)(&cbt[rowb * 64 + ((g ^ (rowb & 7)) * 8)]);
            const short8 b1 = *(const short8*)(&cbt[rowb * 64 + (((g + 4) ^ (rowb & 7)) * 8)]);
            #pragma unroll
            for (int t = 0; t < 8; ++t) {
                f32x4 acc = __builtin_amdgcn_mfma_f32_16x16x32_bf16(a[t][0], b0, ci, 0, 0, 0);
                acc = __builtin_amdgcn_mfma_f32_16x16x32_bf16(a[t][1], b1, acc, 0, 0, 0);
                rm[t][0] = fmaxf(rm[t][0], acc[0]);
                rm[t][1] = fmaxf(rm[t][1], acc[1]);
                rm[t][2] = fmaxf(rm[t][2], acc[2]);
                rm[t][3] = fmaxf(rm[t][3], acc[3]);
            }
        }

        // DPP row-of-16 max (VALU only); lane r16==15 holds each row's max
        #pragma unroll
        for (int t = 0; t < 8; ++t)
            #pragma unroll
            for (int j = 0; j < 4; ++j) {
                FMAX_DPP(rm[t][j], 0x111);   // row_shr:1
                FMAX_DPP(rm[t][j], 0x112);   // row_shr:2
                FMAX_DPP(rm[t][j], 0x114);   // row_shr:4
                FMAX_DPP(rm[t][j], 0x118);   // row_shr:8
            }

        if (r16 == 15) {   // transposed write: cmaxT[ch][q]; row = g*4 + j
            #pragma unroll
            for (int t = 0; t < 8; ++t)
                #pragma unroll
                for (int j = 0; j < 4; ++j)
                    cmaxT[(size_t)chunk * NQ + (qbase + t * 16 + g * 4 + j)] = rm[t][j];
        }
    }
}

// ---- Phase B1: candidate bitmap via ballot (atomic-free, deterministic) ----
__global__ __launch_bounds__(256) void vq_cand(const float* __restrict__ cmaxT,
                                               u64* __restrict__ qmask,
                                               u64* __restrict__ keys) {
    const int tid = threadIdx.x;
    const int lane = tid & 63;
    const int q = blockIdx.x * 256 + tid;
    const int qword = q >> 6;   // wave-uniform
    float v[NCH];
    float m = -3.4e38f;
    #pragma unroll
    for (int j = 0; j < NCH; ++j) {
        v[j] = cmaxT[(size_t)j * NQ + q];
        m = fmaxf(m, v[j]);
    }
    keys[q] = ~0ULL;
    const float thr = m - MARGIN;
    #pragma unroll
    for (int j = 0; j < NCH; ++j) {
        u64 mm = __ballot(v[j] >= thr);
        if (lane == 0) qmask[(size_t)j * (NQ / 64) + qword] = mm;
    }
}

// ---- Phase B2: exact fp32 pass (r20/r22 structure). Launch bound relaxed:
//      the (256,2) cap limited blocks/CU at 2 while VGPR=48 permits 5+ ----
__global__ __launch_bounds__(256) void vq_exact(const float* __restrict__ xf,
                                                const float* __restrict__ cbf,
                                                const float* __restrict__ nh2,
                                                const u64* __restrict__ qmask,
                                                u64* __restrict__ keys) {
    const int ch = blockIdx.x;
    const int slice = blockIdx.y;                 // 0..QSL-1
    const int lane = threadIdx.x & 63;
    const int wid = threadIdx.x >> 6;
    const int kb = ch * CHUNK + wid * 64;
    const int k = kb + lane;

    const u64* wm = qmask + (size_t)ch * (NQ / 64) + slice * (QPS / 64);
    u64 words[QPS / 64];
    u64 any = 0;
    #pragma unroll
    for (int w = 0; w < QPS / 64; ++w) {
        u64 x = wm[w];
        uint32_t lo = __builtin_amdgcn_readfirstlane((uint32_t)x);
        uint32_t hi = __builtin_amdgcn_readfirstlane((uint32_t)(x >> 32));
        words[w] = ((u64)hi << 32) | lo;          // SALU-resident
        any |= words[w];
    }
    if (!any) return;                             // skip code load entirely

    f32x4 cdv[16];                                // this lane's code row
    const f32x4* cb4 = (const f32x4*)(cbf + (size_t)k * DD);
    #pragma unroll
    for (int i = 0; i < 16; ++i) cdv[i] = cb4[i];
    const float nh2k = nh2[k];

    #pragma unroll 1
    for (int w = 0; w < QPS / 64; ++w) {
        u64 sw = words[w];
        while (sw) {
            const int bit = __ffsll((long long)sw) - 1;
            sw &= sw - 1;
            const int q = slice * QPS + w * 64 + bit;
            const f32x4* xr4 = (const f32x4*)(xf + (size_t)q * DD);
            f32x4 xv[16];                          // 16 independent loads in flight
            #pragma unroll
            for (int i = 0; i < 16; ++i) xv[i] = xr4[i];

            float a0 = 0.f, a1 = 0.f, a2 = 0.f, a3 = 0.f;
            #pragma unroll
            for (int i = 0; i < 16; ++i) {         // 4 independent fma chains
                a0 = fmaf(xv[i].x, cdv[i].x, a0);
                a1 = fmaf(xv[i].y, cdv[i].y, a1);
                a2 = fmaf(xv[i].z, cdv[i].z, a2);
                a3 = fmaf(xv[i].w, cdv[i].w, a3);
            }
            float val = -(((a0 + a1) + (a2 + a3)) + nh2k);

            float mn = val;                        // DPP wave64 min (VALU only)
            FMIN_DPP(mn, 0x111);
            FMIN_DPP(mn, 0x112);
            FMIN_DPP(mn, 0x114);
            FMIN_DPP(mn, 0x118);
            FMIN_DPP(mn, 0x142);
            FMIN_DPP(mn, 0x143);
            const float mnall = __uint_as_float(
                __builtin_amdgcn_readlane(__float_as_uint(mn), 63));

            u64 mk = __ballot(val == mnall);       // lane order = code order
            int srcl = __ffsll((long long)mk) - 1; // lowest index on ties
            uint32_t uu = __float_as_uint(mnall);
            uint32_t ub = ((int)uu < 0) ? ~uu : (uu | 0x80000000u);
            u64 key = ((u64)ub << 32) | (unsigned)(kb + srcl);
            if (lane == 0) atomicMin(&keys[q], key);
        }
    }
}

// ---- final: v_q gather + index write (d==0 threads emit indices) ----
__global__ __launch_bounds__(256) void vq_gather(const float* __restrict__ cb,
                                                 const u64* __restrict__ keys,
                                                 float* __restrict__ vq,
                                                 float* __restrict__ oidx) {
    int t = blockIdx.x * 256 + threadIdx.x;
    int l = t & (LL - 1);
    int bd = t >> 11;
    int d = bd & 63;
    int b = bd >> 6;
    int idx = (int)(unsigned)(keys[b * LL + l] & 0x1FFFu);
    vq[t] = cb[idx * DD + d];
    if (d == 0) oidx[b * LL + l] = (float)idx;
}

extern "C" void kernel_launch(void* const* d_in, const int* in_sizes, int n_in,
                              void* d_out, int out_size, void* d_ws, size_t ws_size,
                              hipStream_t stream) {
    const float* ze = (const float*)d_in[0];
    const float* cb = (const float*)d_in[1];
    float* out = (float*)d_out;

    short* xb = (short*)d_out;                                    // [0,4MB)
    float* cmaxT = (float*)((char*)d_out + (size_t)NQ * DD * 2);  // [4,8MB)
    float* xf = (float*)d_out;                                    // [0,8MB) after cand
    u64* qmask = (u64*)(out + VQ_SIZE);                           // 128KB indices region
    float* nh2 = (float*)d_ws;                                    // [0,32K)
    u64* keys = (u64*)((char*)d_ws + (size_t)KK * 4);             // [32K,288K)
    short* cb16s = (short*)((char*)d_ws + (size_t)544 * 1024);    // [544K,544K+1M)
    float* oidx = out + VQ_SIZE;

    const bool cb16 = ws_size >= (size_t)(544 * 1024 + (size_t)KK * DD * 2);

    dim3 gx(BB, LL / 64);
    prep_x<<<gx, 256, 0, stream>>>(ze, xb, cb, nh2);   // nh2 fused (y==0 blocks)
    if (cb16) prep_cb16<<<(KK * 8) / 256, 256, 0, stream>>>(cb, cb16s);

    dim3 gs(NQ / 512, NCH / 2);   // 2 chunks per block
    if (cb16) vq_screen<true><<<gs, 256, 0, stream>>>(cb, cb16s, nh2, xb, cmaxT);
    else      vq_screen<false><<<gs, 256, 0, stream>>>(cb, cb16s, nh2, xb, cmaxT);

    vq_cand<<<NQ / 256, 256, 0, stream>>>(cmaxT, qmask, keys);

    prep_xf<<<gx, 256, 0, stream>>>(ze, xf);   // overwrites xb+cmaxT (both dead)

    dim3 ge(NCH, QSL);
    vq_exact<<<ge, 256, 0, stream>>>(xf, cb, nh2, qmask, keys);

    vq_gather<<<VQ_SIZE / 256, 256, 0, stream>>>(cb, keys, out, oidx);
}